// Round 12
// baseline (121.888 us; speedup 1.0000x reference)
//
#include <hip/hip_runtime.h>

#define H 1024
#define W 1024
#define NIMG 8
#define CPT 8                  // output cols per thread
#define VC 16                  // V-columns per thread (CPT + 8 halo)
#define TH 16                  // output rows per band
#define NBANDS (H / TH)        // 64
#define NWAVES (2 * NBANDS * NIMG)   // 1024 one-wave blocks = 1 wave/SIMD
#define EPS 1e-5f

__device__ __forceinline__ float4 ld4(const float* p) {
  return *reinterpret_cast<const float4*>(p);
}

struct Row { float4 i0,i1,i2,i3, j0,j1,j2,j3; };   // raw, unmasked

__device__ __forceinline__ void load_row(const float* __restrict__ Ir,
                                         const float* __restrict__ Jr,
                                         int xl, int X, int xr, Row& o) {
  // 8 raw float4 loads, NO uses here -> waitcnt lands at the consumer
  o.i0 = ld4(Ir + xl); o.i1 = ld4(Ir + X); o.i2 = ld4(Ir + X + 4); o.i3 = ld4(Ir + xr);
  o.j0 = ld4(Jr + xl); o.j1 = ld4(Jr + X); o.j2 = ld4(Jr + X + 4); o.j3 = ld4(Jr + xr);
}

// Vertical-first: V[c] = running 9-row column sums of {I,J,I2,J2,IJ}.
// Horizontal 9-box becomes an in-register slide over V at emit time.
__global__ __launch_bounds__(64, 1)
void ncc_main(const float* __restrict__ I, const float* __restrict__ J,
              float* __restrict__ partial) {
  const int lane = threadIdx.x;            // 0..63
  const int xh   = blockIdx.x;             // 0/1 image half
  const int band = blockIdx.y;             // 0..63
  const int n    = blockIdx.z;
  const int X  = xh * 512 + lane * CPT;    // first output col
  const int y0 = band * TH;
  const bool okL = (X >= 4);
  const bool okR = (X + 12 <= W);
  const int xl = okL ? X - 4 : X;          // clamped halo addresses
  const int xr = okR ? X + 8 : X + 4;
  const float* Ip = I + (size_t)n * H * W;
  const float* Jp = J + (size_t)n * H * W;

  float vI[VC], vJ[VC], vII[VC], vJJ[VC], vIJ[VC];
  #pragma unroll
  for (int c = 0; c < VC; ++c) { vI[c]=vJ[c]=vII[c]=vJJ[c]=vIJ[c]=0.f; }
  float acc = 0.f;
  const float inv81 = 1.0f / 81.0f;

  // masked unpack + accumulate with sign (masks applied at USE, not at load)
  auto accum = [&](const Row& r, float sgn) {
    float a[VC], b[VC];
    a[0]=okL?r.i0.x:0.f; a[1]=okL?r.i0.y:0.f; a[2]=okL?r.i0.z:0.f; a[3]=okL?r.i0.w:0.f;
    b[0]=okL?r.j0.x:0.f; b[1]=okL?r.j0.y:0.f; b[2]=okL?r.j0.z:0.f; b[3]=okL?r.j0.w:0.f;
    a[4]=r.i1.x; a[5]=r.i1.y; a[6]=r.i1.z; a[7]=r.i1.w;
    b[4]=r.j1.x; b[5]=r.j1.y; b[6]=r.j1.z; b[7]=r.j1.w;
    a[8]=r.i2.x; a[9]=r.i2.y; a[10]=r.i2.z; a[11]=r.i2.w;
    b[8]=r.j2.x; b[9]=r.j2.y; b[10]=r.j2.z; b[11]=r.j2.w;
    a[12]=okR?r.i3.x:0.f; a[13]=okR?r.i3.y:0.f; a[14]=okR?r.i3.z:0.f; a[15]=okR?r.i3.w:0.f;
    b[12]=okR?r.j3.x:0.f; b[13]=okR?r.j3.y:0.f; b[14]=okR?r.j3.z:0.f; b[15]=okR?r.j3.w:0.f;
    #pragma unroll
    for (int c = 0; c < VC; ++c) {
      float sa = sgn * a[c];
      vI[c]  += sa;
      vJ[c]  = fmaf(sgn, b[c], vJ[c]);
      vII[c] = fmaf(sa, a[c], vII[c]);
      vJJ[c] = fmaf(sgn * b[c], b[c], vJJ[c]);
      vIJ[c] = fmaf(sa, b[c], vIJ[c]);
    }
  };

  // horizontal 9-slide over V -> 8 outputs (depends ONLY on V)
  auto emitrow = [&]() {
    float hI=0.f, hJ=0.f, hII=0.f, hJJ=0.f, hIJ=0.f;
    #pragma unroll
    for (int k = 0; k < 9; ++k) {
      hI += vI[k]; hJ += vJ[k]; hII += vII[k]; hJJ += vJJ[k]; hIJ += vIJ[k];
    }
    #pragma unroll
    for (int c = 0; c < CPT; ++c) {
      float cross = fmaf(-(hI * hJ), inv81, hIJ);
      float Iv    = fmaf(-(hI * hI), inv81, hII);
      float Jv    = fmaf(-(hJ * hJ), inv81, hJJ);
      acc = fmaf(cross * cross,
                 __builtin_amdgcn_rcpf(fmaf(Iv, Jv, EPS)), acc);
      if (c < CPT - 1) {
        hI  += vI[c+9]  - vI[c];   hJ  += vJ[c+9]  - vJ[c];
        hII += vII[c+9] - vII[c];  hJJ += vJJ[c+9] - vJJ[c];
        hIJ += vIJ[c+9] - vIJ[c];
      }
    }
  };

  // ---- warm-up: V <- rows y0-4 .. y0+4 (pair-pipelined loads) ----
  #pragma unroll 1
  for (int k = 0; k < 9; k += 2) {
    const int r1 = y0 - 4 + k, r2 = r1 + 1;
    const bool v1 = (unsigned)r1 < (unsigned)H;          // uniform
    const bool v2 = (k + 1 < 9) && ((unsigned)r2 < (unsigned)H);
    Row A, B;
    if (v1) load_row(Ip + (size_t)r1 * W, Jp + (size_t)r1 * W, xl, X, xr, A);
    if (v2) load_row(Ip + (size_t)r2 * W, Jp + (size_t)r2 * W, xl, X, xr, B);
    if (v1) accum(A, 1.0f);
    if (v2) accum(B, 1.0f);
  }

  // ---- steady: issue loads -> emit y (independent) -> wait+update ----
  #pragma unroll 1
  for (int y = y0; y < y0 + TH - 1; ++y) {
    const int re = y + 5;                 // entering row (for y+1's window)
    const int rl = y - 4;                 // leaving row
    const bool ev = re < H;               // uniform
    const bool lv = rl >= 0;              // uniform
    Row E, L;
    if (ev) load_row(Ip + (size_t)re * W, Jp + (size_t)re * W, xl, X, xr, E);
    if (lv) load_row(Ip + (size_t)rl * W, Jp + (size_t)rl * W, xl, X, xr, L);
    emitrow();                            // fills the load shadow with VALU
    if (ev) accum(E,  1.0f);
    if (lv) accum(L, -1.0f);
  }
  emitrow();                              // last row of the band

  // ---- wave reduction -> one partial per wave ----
  #pragma unroll
  for (int off = 32; off > 0; off >>= 1)
    acc += __shfl_down(acc, off, 64);
  if (lane == 0) {
    const int wid = ((int)n * NBANDS + band) * 2 + xh;
    partial[wid] = acc;
  }
}

__global__ __launch_bounds__(256)
void ncc_reduce(const float* __restrict__ partial, float* __restrict__ out) {
  __shared__ float red[4];
  const int tid = threadIdx.x;
  const float4* p4 = reinterpret_cast<const float4*>(partial);
  float s = 0.f;
  #pragma unroll
  for (int i = tid; i < NWAVES / 4; i += 256) {
    float4 v = p4[i];
    s += (v.x + v.y) + (v.z + v.w);
  }
  #pragma unroll
  for (int off = 32; off > 0; off >>= 1)
    s += __shfl_down(s, off, 64);
  if ((tid & 63) == 0) red[tid >> 6] = s;
  __syncthreads();
  if (tid == 0)
    out[0] = (red[0] + red[1] + red[2] + red[3]) *
             (1.0f / (float)((size_t)NIMG * H * W));
}

extern "C" void kernel_launch(void* const* d_in, const int* in_sizes, int n_in,
                              void* d_out, int out_size, void* d_ws, size_t ws_size,
                              hipStream_t stream) {
  const float* I = (const float*)d_in[0];
  const float* J = (const float*)d_in[1];
  float* out     = (float*)d_out;
  float* partial = (float*)d_ws;            // 1024 * 4 B

  dim3 grid(2, NBANDS, NIMG);               // 2 x 64 x 8 = 1024 one-wave blocks
  hipLaunchKernelGGL(ncc_main, grid, dim3(64), 0, stream, I, J, partial);
  hipLaunchKernelGGL(ncc_reduce, dim3(1), dim3(256), 0, stream, partial, out);
}